// Round 6
// baseline (640.859 us; speedup 1.0000x reference)
//
#include <hip/hip_runtime.h>
#include <stdint.h>
#include <type_traits>

typedef __attribute__((ext_vector_type(8))) short short8;
typedef __attribute__((ext_vector_type(4))) float f32x4;

#define S_LEN 4096
#define D_DIM 256
#define BATCH 4

__device__ __forceinline__ f32x4 mfma16(short8 a, short8 b, f32x4 c) {
    return __builtin_amdgcn_mfma_f32_16x16x32_bf16(a, b, c, 0, 0, 0);
}

// fp32 -> bf16 bits, round-to-nearest-even (matches numpy/ml_dtypes)
__device__ __forceinline__ short f2bf(float x) {
    uint32_t u = __float_as_uint(x);
    uint32_t r = (u + 0x7FFFu + ((u >> 16) & 1u)) >> 16;
    return (short)r;
}

__device__ __forceinline__ short8 load8(const short* p) {  // bf16 bits
    return *reinterpret_cast<const short8*>(p);
}
__device__ __forceinline__ short8 load8(const float* p) {  // fp32 -> bf16
    f32x4 a = *reinterpret_cast<const f32x4*>(p);
    f32x4 b = *reinterpret_cast<const f32x4*>(p + 4);
    short8 r;
#pragma unroll
    for (int i = 0; i < 4; ++i) r[i] = f2bf(a[i]);
#pragma unroll
    for (int i = 0; i < 4; ++i) r[i + 4] = f2bf(b[i]);
    return r;
}

// ---- transpose four 256x256 fp32 weights into bf16 ws (WT[z][f][d] = W[z][d][f]) ----
__global__ __launch_bounds__(256) void transpose_w(
    const float* __restrict__ wq, const float* __restrict__ wk,
    const float* __restrict__ wv, const float* __restrict__ wo,
    short* __restrict__ out)
{
    __shared__ float t[16][17];
    const float* in = blockIdx.z == 0 ? wq : blockIdx.z == 1 ? wk
                    : blockIdx.z == 2 ? wv : wo;
    short* o = out + (size_t)blockIdx.z * 65536;
    const int x0 = blockIdx.x * 16, y0 = blockIdx.y * 16;
    const int tx = threadIdx.x, ty = threadIdx.y;
    t[ty][tx] = in[(y0 + ty) * 256 + x0 + tx];
    __syncthreads();
    o[(size_t)(x0 + ty) * 256 + y0 + tx] = f2bf(t[tx][ty]);
}

// ---- C[M][N] = A[M][256] * Bt[N][256]^T (+bias fp32), fp32 accum ----
// bias_mode: 0 none, 1 bias[col], 2 bias[row]
// OMODE: 0 row-major C[row*ldc+col]
//        1 Q-frag  QF[b][jt<256][kk<8][lane][e]        (row=token, col=feat)
//        2 K-frag  KF[b][kt<64][kk<8][n<4][lane][e]    (row=token, col=feat)
//        3 V-frag  VF[b][kt<64][k2<2][nf<16][lane][e]  (row=feat,  col=token)
template <typename TA, typename TB, typename TC, int OMODE>
__global__ __launch_bounds__(256) void gemm_bt(
    const TA* __restrict__ A, const TB* __restrict__ Bt,
    const float* __restrict__ bias, TC* __restrict__ C,
    int M, int N, int ldc, int bias_mode)
{
    const int K = 256;
    __shared__ short As[128 * 64];
    __shared__ short Bs[128 * 64];
    const int tid = threadIdx.x;
    const int lane = tid & 63;
    const int w = tid >> 6;
    const int wr = w >> 1, wc = w & 1;
    const int lo = lane & 15, hi = lane >> 4;
    const size_t m0 = (size_t)blockIdx.y * 128, n0 = (size_t)blockIdx.x * 128;

    f32x4 acc[4][4] = {};

    for (int kt = 0; kt < 4; ++kt) {
        short8 va[4], vb[4];
#pragma unroll
        for (int i = 0; i < 4; ++i) {
            int s = tid + 256 * i;                 // 16B(bf16) slot 0..1023
            int row = s >> 3, ke = (s & 7) * 8;    // 8 slots per 64-elem row
            va[i] = load8(A  + (m0 + row) * K + kt * 64 + ke);
            vb[i] = load8(Bt + (n0 + row) * K + kt * 64 + ke);
        }
#pragma unroll
        for (int i = 0; i < 4; ++i) {
            int s = tid + 256 * i;
            *reinterpret_cast<short8*>(&As[s * 8]) = va[i];
            *reinterpret_cast<short8*>(&Bs[s * 8]) = vb[i];
        }
        __syncthreads();
#pragma unroll
        for (int kk = 0; kk < 2; ++kk) {
            short8 af[4], bf[4];
#pragma unroll
            for (int m = 0; m < 4; ++m)
                af[m] = *reinterpret_cast<const short8*>(&As[(wr * 64 + m * 16 + lo) * 64 + kk * 32 + hi * 8]);
#pragma unroll
            for (int n = 0; n < 4; ++n)
                bf[n] = *reinterpret_cast<const short8*>(&Bs[(wc * 64 + n * 16 + lo) * 64 + kk * 32 + hi * 8]);
#pragma unroll
            for (int m = 0; m < 4; ++m)
#pragma unroll
                for (int n = 0; n < 4; ++n)
                    acc[m][n] = mfma16(af[m], bf[n], acc[m][n]);
        }
        __syncthreads();
    }

#pragma unroll
    for (int m = 0; m < 4; ++m) {
#pragma unroll
        for (int n = 0; n < 4; ++n) {
#pragma unroll
            for (int j = 0; j < 4; ++j) {
                size_t row = m0 + wr * 64 + m * 16 + hi * 4 + j;
                size_t col = n0 + wc * 64 + n * 16 + lo;
                float v = acc[m][n][j];
                if (bias_mode == 1)      v += bias[col];
                else if (bias_mode == 2) v += bias[row];

                if constexpr (OMODE == 0) {
                    if constexpr (std::is_same<TC, float>::value)
                        C[row * (size_t)ldc + col] = v;
                    else
                        C[row * (size_t)ldc + col] = f2bf(v);
                } else if constexpr (OMODE == 1) {
                    int b = (int)(row >> 12), R = (int)(row & 4095);
                    int jt = R >> 4, lk = R & 15;
                    int kk = (int)(col >> 5), q = (int)(col & 31), hk = q >> 3, e = q & 7;
                    size_t idx = ((((size_t)(b * 256 + jt) * 8 + kk) * 64) + hk * 16 + lk) * 8 + e;
                    C[idx] = f2bf(v);
                } else if constexpr (OMODE == 2) {
                    int b = (int)(row >> 12), R = (int)(row & 4095);
                    int ktile = R >> 6, nn = (R >> 4) & 3, lk = R & 15;
                    int kk = (int)(col >> 5), q = (int)(col & 31), hk = q >> 3, e = q & 7;
                    size_t idx = (((((size_t)(b * 64 + ktile) * 8 + kk) * 4 + nn) * 64) + hk * 16 + lk) * 8 + e;
                    C[idx] = f2bf(v);
                } else {  // OMODE == 3: row = feature f, col = global token
                    int b = (int)(col >> 12), T = (int)(col & 4095);
                    int ktile = T >> 6, t6 = T & 63, k2 = t6 >> 5, r5 = t6 & 31;
                    int hk = r5 >> 3, e = r5 & 7;
                    int nf = (int)(row >> 4), lk = (int)(row & 15);
                    size_t idx = (((((size_t)(b * 64 + ktile) * 2 + k2) * 16 + nf) * 64) + hk * 16 + lk) * 8 + e;
                    C[idx] = f2bf(v);
                }
            }
        }
    }
}

// ---- causal flash attention, in-block split-K, fragment-major inputs ----
// 1D grid: g -> jt = 255-(g>>2) (LPT), b = g&3 (batch->XCD affinity under %8
// round-robin dispatch: batch b lands on XCDs {b, b+4} only -> 8MB/XCD K/V set).
// Block = 4 waves, ONE 16-row q-tile; wave w handles k-tiles w, w+4, ...
// Sequential LDS merge (1 buffer, ~25KB total LDS -> 6 blocks/CU).
__global__ __launch_bounds__(256, 6) void attn_fwd(
    const short* __restrict__ Qf, const short* __restrict__ Kf,
    const short* __restrict__ Vf, short* __restrict__ Sc)
{
    __shared__ short P[4][16 * 64];      // 8 KB
    __shared__ float OB[16][260];        // 16.6 KB
    __shared__ float MLm[16], MLl[16];   // 128 B

    const int tid = threadIdx.x;
    const int lane = tid & 63;
    const int w = tid >> 6;
    const int lo = lane & 15, hi = lane >> 4;
    const int g = (int)blockIdx.x;
    const int jt = 255 - (g >> 2);       // longest tiles first
    const int b = g & 3;
    const int q0 = jt * 16;
    short* Sb = Sc + (size_t)b * S_LEN * D_DIM;

    short8 qv[8];
#pragma unroll
    for (int kk = 0; kk < 8; ++kk)
        qv[kk] = load8(Qf + (((size_t)(b * 256 + jt) * 8 + kk) * 64 + lane) * 8);

    f32x4 o[16] = {};
    float mrow[4] = {-1e30f, -1e30f, -1e30f, -1e30f};
    float lrow[4] = {0.f, 0.f, 0.f, 0.f};

    const int nkt = (q0 >> 6) + 1;
    for (int kt = w; kt < nkt; kt += 4) {
        const int k0 = kt * 64;
        const short* Kt = Kf + (size_t)(b * 64 + kt) * (8 * 4 * 64 * 8);
        const short* Vt = Vf + (size_t)(b * 64 + kt) * (2 * 16 * 64 * 8);

        f32x4 s4[4] = {};
#pragma unroll
        for (int kk = 0; kk < 8; ++kk) {
#pragma unroll
            for (int n = 0; n < 4; ++n) {
                short8 kf = load8(Kt + (((size_t)kk * 4 + n) * 64 + lane) * 8);
                s4[n] = mfma16(qv[kk], kf, s4[n]);
            }
        }

        // hoist first 8 V-frag loads: in flight under the softmax VALU section
        short8 vpre[8];
#pragma unroll
        for (int nf = 0; nf < 8; ++nf)
            vpre[nf] = load8(Vt + ((size_t)nf * 64 + lane) * 8);

        const bool diag = (kt == nkt - 1);
        float pm[4] = {-1e30f, -1e30f, -1e30f, -1e30f};
#pragma unroll
        for (int n = 0; n < 4; ++n) {
#pragma unroll
            for (int j = 0; j < 4; ++j) {
                float v = s4[n][j] * 0.0625f;  // 1/sqrt(256)
                if (diag) {
                    int r = q0 + hi * 4 + j, c = k0 + n * 16 + lo;
                    if (c > r) v = -1e30f;     // causal mask
                }
                s4[n][j] = v;
                pm[j] = fmaxf(pm[j], v);
            }
        }
#pragma unroll
        for (int off = 1; off < 16; off <<= 1)
#pragma unroll
            for (int j = 0; j < 4; ++j)
                pm[j] = fmaxf(pm[j], __shfl_xor(pm[j], off));

        float sc[4], lsum[4];
#pragma unroll
        for (int j = 0; j < 4; ++j) {
            float mn = fmaxf(mrow[j], pm[j]);
            sc[j] = __expf(mrow[j] - mn);
            mrow[j] = mn;
            lsum[j] = 0.f;
        }
#pragma unroll
        for (int n = 0; n < 4; ++n)
#pragma unroll
            for (int j = 0; j < 4; ++j) {
                float p = __expf(s4[n][j] - mrow[j]);
                s4[n][j] = p;
                lsum[j] += p;
            }
#pragma unroll
        for (int off = 1; off < 16; off <<= 1)
#pragma unroll
            for (int j = 0; j < 4; ++j)
                lsum[j] += __shfl_xor(lsum[j], off);
#pragma unroll
        for (int j = 0; j < 4; ++j)
            lrow[j] = lrow[j] * sc[j] + lsum[j];
#pragma unroll
        for (int nf = 0; nf < 16; ++nf)
#pragma unroll
            for (int j = 0; j < 4; ++j)
                o[nf][j] *= sc[j];

        // P (fp32, C/D layout) -> LDS -> A-frag layout (bf16)
#pragma unroll
        for (int n = 0; n < 4; ++n)
#pragma unroll
            for (int j = 0; j < 4; ++j)
                P[w][(hi * 4 + j) * 64 + n * 16 + lo] = f2bf(s4[n][j]);

        {
            short8 pa = *reinterpret_cast<const short8*>(&P[w][lo * 64 + hi * 8]);
#pragma unroll
            for (int nf = 0; nf < 8; ++nf)
                o[nf] = mfma16(pa, vpre[nf], o[nf]);
#pragma unroll
            for (int nf = 8; nf < 16; ++nf) {
                short8 vf = load8(Vt + ((size_t)nf * 64 + lane) * 8);
                o[nf] = mfma16(pa, vf, o[nf]);
            }
            short8 pb = *reinterpret_cast<const short8*>(&P[w][lo * 64 + 32 + hi * 8]);
#pragma unroll
            for (int nf = 0; nf < 16; ++nf) {
                short8 vf = load8(Vt + (((size_t)16 + nf) * 64 + lane) * 8);
                o[nf] = mfma16(pb, vf, o[nf]);
            }
        }
    }

    // ---- sequential merge of 4 per-wave partials into wave 0 ----
    for (int src = 1; src < 4; ++src) {
        if (w == src) {
#pragma unroll
            for (int nf = 0; nf < 16; ++nf)
#pragma unroll
                for (int j = 0; j < 4; ++j)
                    OB[hi * 4 + j][nf * 16 + lo] = o[nf][j];
            if (lo == 0)
#pragma unroll
                for (int j = 0; j < 4; ++j) {
                    MLm[hi * 4 + j] = mrow[j];
                    MLl[hi * 4 + j] = lrow[j];
                }
        }
        __syncthreads();
        if (w == 0) {
            float sa[4], sb[4];
#pragma unroll
            for (int j = 0; j < 4; ++j) {
                float mb = MLm[hi * 4 + j];
                float lb = MLl[hi * 4 + j];
                float M = fmaxf(mrow[j], mb);
                sa[j] = __expf(mrow[j] - M);
                sb[j] = __expf(mb - M);
                mrow[j] = M;
                lrow[j] = lrow[j] * sa[j] + lb * sb[j];
            }
#pragma unroll
            for (int nf = 0; nf < 16; ++nf)
#pragma unroll
                for (int j = 0; j < 4; ++j)
                    o[nf][j] = o[nf][j] * sa[j] + OB[hi * 4 + j][nf * 16 + lo] * sb[j];
        }
        __syncthreads();
    }

    if (w == 0) {
#pragma unroll
        for (int nf = 0; nf < 16; ++nf)
#pragma unroll
            for (int j = 0; j < 4; ++j) {
                size_t row = q0 + hi * 4 + j;
                size_t col = nf * 16 + lo;
                Sb[row * D_DIM + col] = f2bf(o[nf][j] / lrow[j]);
            }
    }
}

extern "C" void kernel_launch(void* const* d_in, const int* in_sizes, int n_in,
                              void* d_out, int out_size, void* d_ws, size_t ws_size,
                              hipStream_t stream)
{
    const float* x  = (const float*)d_in[0];
    // d_in[1] = mask (int32 tril) — causality applied analytically, not read
    const float* wq = (const float*)d_in[2];
    const float* bq = (const float*)d_in[3];
    const float* wk = (const float*)d_in[4];
    const float* bk = (const float*)d_in[5];
    const float* wv = (const float*)d_in[6];
    const float* bv = (const float*)d_in[7];
    const float* wo = (const float*)d_in[8];
    const float* bo = (const float*)d_in[9];
    float* out = (float*)d_out;

    const size_t NTOK = (size_t)BATCH * S_LEN;          // 16384
    short* WT  = (short*)d_ws;                          // 4 * 65536 bf16
    short* QF  = WT + 4 * 65536;
    short* KF  = QF + NTOK * D_DIM;
    short* VF  = KF + NTOK * D_DIM;
    short* Sw  = QF;   // alias: tile jt's Q-frags occupy exactly the 8KB its S rows use;
                       // each block reads all its Q before writing its S. Safe.

    const int M = (int)NTOK;

    transpose_w<<<dim3(16, 16, 4), dim3(16, 16), 0, stream>>>(wq, wk, wv, wo, WT);
    gemm_bt<float, short, short, 1><<<dim3(2, M / 128), 256, 0, stream>>>(x, WT,         bq, QF, M, 256, 256, 1);
    gemm_bt<float, short, short, 2><<<dim3(2, M / 128), 256, 0, stream>>>(x, WT + 65536, bk, KF, M, 256, 256, 1);
    gemm_bt<short, float, short, 3><<<dim3(M / 128, 2), 256, 0, stream>>>(WT + 2 * 65536, x, bv, VF, 256, M, M, 2);
    attn_fwd<<<dim3(1024), 256, 0, stream>>>(QF, KF, VF, Sw);
    gemm_bt<short, short, float, 0><<<dim3(2, M / 128), 256, 0, stream>>>(Sw, WT + 3 * 65536, bo, out, M, 256, 256, 1);
}

// Round 8
// 228.972 us; speedup vs baseline: 2.7989x; 2.7989x over previous
//
#include <hip/hip_runtime.h>
#include <stdint.h>
#include <type_traits>

typedef __attribute__((ext_vector_type(8))) short short8;
typedef __attribute__((ext_vector_type(4))) short s16x4;
typedef __attribute__((ext_vector_type(4))) float f32x4;

#define S_LEN 4096
#define D_DIM 256
#define BATCH 4

__device__ __forceinline__ f32x4 mfma16(short8 a, short8 b, f32x4 c) {
    return __builtin_amdgcn_mfma_f32_16x16x32_bf16(a, b, c, 0, 0, 0);
}

// fp32 -> bf16 bits, round-to-nearest-even (matches numpy/ml_dtypes)
__device__ __forceinline__ short f2bf(float x) {
    uint32_t u = __float_as_uint(x);
    uint32_t r = (u + 0x7FFFu + ((u >> 16) & 1u)) >> 16;
    return (short)r;
}

// async global->LDS, 16B per lane. LDS dest wave-uniform base; HW adds lane*16.
__device__ __forceinline__ void gload16(const short* g, short* l) {
    __builtin_amdgcn_global_load_lds(
        (const __attribute__((address_space(1))) void*)g,
        (__attribute__((address_space(3))) void*)l, 16, 0, 0);
}

// ---- x fp32 -> bf16 ----
__global__ __launch_bounds__(256) void xbf_conv(
    const float* __restrict__ x, short* __restrict__ xb)
{
    int i = blockIdx.x * 256 + threadIdx.x;   // 8 elems per thread
    f32x4 a = *reinterpret_cast<const f32x4*>(x + (size_t)i * 8);
    f32x4 b = *reinterpret_cast<const f32x4*>(x + (size_t)i * 8 + 4);
    short8 r;
#pragma unroll
    for (int k = 0; k < 4; ++k) r[k] = f2bf(a[k]);
#pragma unroll
    for (int k = 0; k < 4; ++k) r[k + 4] = f2bf(b[k]);
    *reinterpret_cast<short8*>(xb + (size_t)i * 8) = r;
}

// ---- transpose four 256x256 fp32 weights into bf16 ws (WT[z][f][d] = W[z][d][f]) ----
__global__ __launch_bounds__(256) void transpose_w(
    const float* __restrict__ wq, const float* __restrict__ wk,
    const float* __restrict__ wv, const float* __restrict__ wo,
    short* __restrict__ out)
{
    __shared__ float t[16][17];
    const float* in = blockIdx.z == 0 ? wq : blockIdx.z == 1 ? wk
                    : blockIdx.z == 2 ? wv : wo;
    short* o = out + (size_t)blockIdx.z * 65536;
    const int x0 = blockIdx.x * 16, y0 = blockIdx.y * 16;
    const int tx = threadIdx.x, ty = threadIdx.y;
    t[ty][tx] = in[(y0 + ty) * 256 + x0 + tx];
    __syncthreads();
    o[(size_t)(x0 + ty) * 256 + y0 + tx] = f2bf(t[tx][ty]);
}

// ---- C[M][N] = A[M][256] * Bt[N][256]^T (+bias fp32), bf16 in, fp32 accum ----
// bias_mode: 0 none, 1 bias[col], 2 bias[row]
// OMODE: 0 row-major; 1 Q-frag; 2 K-frag; 3 V-frag (layouts as in attn)
template <typename TC, int OMODE>
__global__ __launch_bounds__(256) void gemm_bt(
    const short* __restrict__ A, const short* __restrict__ Bt,
    const float* __restrict__ bias, TC* __restrict__ C,
    int M, int N, int ldc, int bias_mode)
{
    __shared__ short As[128 * 64];
    __shared__ short Bs[128 * 64];
    const int tid = threadIdx.x;
    const int lane = tid & 63;
    const int w = tid >> 6;
    const int wr = w >> 1, wc = w & 1;
    const int lo = lane & 15, hi = lane >> 4;
    const size_t m0 = (size_t)blockIdx.y * 128, n0 = (size_t)blockIdx.x * 128;

    f32x4 acc[4][4] = {};

    for (int kt = 0; kt < 4; ++kt) {
#pragma unroll
        for (int i = 0; i < 4; ++i) {
            int c = i * 4 + w;                     // wave chunk 0..15
            int s = c * 64 + lane;                 // 16B slot 0..1023
            int row = s >> 3, ke = (s & 7) * 8;    // 8 slots per 64-elem row
            gload16(A  + (m0 + row) * 256 + kt * 64 + ke, As + c * 512);
            gload16(Bt + (n0 + row) * 256 + kt * 64 + ke, Bs + c * 512);
        }
        __syncthreads();
#pragma unroll
        for (int kk = 0; kk < 2; ++kk) {
            short8 af[4], bf[4];
#pragma unroll
            for (int m = 0; m < 4; ++m)
                af[m] = *reinterpret_cast<const short8*>(&As[(wr * 64 + m * 16 + lo) * 64 + kk * 32 + hi * 8]);
#pragma unroll
            for (int n = 0; n < 4; ++n)
                bf[n] = *reinterpret_cast<const short8*>(&Bs[(wc * 64 + n * 16 + lo) * 64 + kk * 32 + hi * 8]);
#pragma unroll
            for (int m = 0; m < 4; ++m)
#pragma unroll
                for (int n = 0; n < 4; ++n)
                    acc[m][n] = mfma16(af[m], bf[n], acc[m][n]);
        }
        __syncthreads();
    }

#pragma unroll
    for (int m = 0; m < 4; ++m) {
#pragma unroll
        for (int n = 0; n < 4; ++n) {
#pragma unroll
            for (int j = 0; j < 4; ++j) {
                size_t row = m0 + wr * 64 + m * 16 + hi * 4 + j;
                size_t col = n0 + wc * 64 + n * 16 + lo;
                float v = acc[m][n][j];
                if (bias_mode == 1)      v += bias[col];
                else if (bias_mode == 2) v += bias[row];

                if constexpr (OMODE == 0) {
                    if constexpr (std::is_same<TC, float>::value)
                        C[row * (size_t)ldc + col] = v;
                    else
                        C[row * (size_t)ldc + col] = f2bf(v);
                } else if constexpr (OMODE == 1) {
                    int b = (int)(row >> 12), R = (int)(row & 4095);
                    int jt = R >> 4, lk = R & 15;
                    int kk = (int)(col >> 5), q = (int)(col & 31), hk = q >> 3, e = q & 7;
                    size_t idx = ((((size_t)(b * 256 + jt) * 8 + kk) * 64) + hk * 16 + lk) * 8 + e;
                    C[idx] = f2bf(v);
                } else if constexpr (OMODE == 2) {
                    int b = (int)(row >> 12), R = (int)(row & 4095);
                    int ktile = R >> 6, nn = (R >> 4) & 3, lk = R & 15;
                    int kk = (int)(col >> 5), q = (int)(col & 31), hk = q >> 3, e = q & 7;
                    size_t idx = (((((size_t)(b * 64 + ktile) * 8 + kk) * 4 + nn) * 64) + hk * 16 + lk) * 8 + e;
                    C[idx] = f2bf(v);
                } else {  // OMODE == 3: row = feature f, col = global token
                    int b = (int)(col >> 12), T = (int)(col & 4095);
                    int ktile = T >> 6, t6 = T & 63, k2 = t6 >> 5, r5 = t6 & 31;
                    int hk = r5 >> 3, e = r5 & 7;
                    int nf = (int)(row >> 4), lk = (int)(row & 15);
                    size_t idx = (((((size_t)(b * 64 + ktile) * 2 + k2) * 16 + nf) * 64) + hk * 16 + lk) * 8 + e;
                    C[idx] = f2bf(v);
                }
            }
        }
    }
}

// ---- causal flash attention, LDS-staged K/V, q-split waves, cross-block split-K ----
// Block: (j, b, p). q-block = 64 rows [j*64, j*64+64); wave w owns rows w*16..w*16+15.
// K-tiles kt = p, p+NSPLIT, ... <= j staged in LDS (K 32KB + V 32KB), shared by 4 waves.
// DIRECT: normalize and write S. Else: write partial (O fp32, m, l) for merge kernel.
template <int NSPLIT, bool DIRECT>
__global__ __launch_bounds__(256) void attn_fwd(
    const short* __restrict__ Qf, const short* __restrict__ Kf,
    const short* __restrict__ Vf, float* __restrict__ PO,
    float* __restrict__ PML, short* __restrict__ Sc)
{
    __shared__ short Ks[64 * 256];   // 32 KB
    __shared__ short Vs[64 * 256];   // 32 KB
    __shared__ short P[4][16 * 64];  // 8 KB

    const int tid = threadIdx.x;
    const int lane = tid & 63;
    const int w = tid >> 6;
    const int lo = lane & 15, hi = lane >> 4;
    const int bx = (int)blockIdx.x;
    const int j = 63 - bx / (BATCH * NSPLIT);   // LPT: longest q-blocks first
    const int r = bx % (BATCH * NSPLIT);
    const int b = r / NSPLIT;                   // bx%8 pins batch to 2 XCDs (NSPLIT=2)
    const int p = r % NSPLIT;
    const int q0 = j * 64;

    short8 qv[8];
#pragma unroll
    for (int kk = 0; kk < 8; ++kk)
        qv[kk] = *reinterpret_cast<const short8*>(
            Qf + (((size_t)(b * 256 + j * 4 + w) * 8 + kk) * 64 + lane) * 8);

    f32x4 o[16] = {};
    float mrow[4] = {-1e30f, -1e30f, -1e30f, -1e30f};
    float lrow[4] = {0.f, 0.f, 0.f, 0.f};

    for (int kt = p; kt <= j; kt += NSPLIT) {
        const short* Kt = Kf + (size_t)(b * 64 + kt) * 16384;
        const short* Vt = Vf + (size_t)(b * 64 + kt) * 16384;
#pragma unroll
        for (int c4 = 0; c4 < 8; ++c4) {
            int c = c4 * 4 + w;                 // 1KB chunk per call
            gload16(Kt + c * 512 + lane * 8, Ks + c * 512);
            gload16(Vt + c * 512 + lane * 8, Vs + c * 512);
        }
        __syncthreads();                        // drains vmcnt -> tiles ready

        f32x4 s4[4] = {};
#pragma unroll
        for (int kk = 0; kk < 8; ++kk) {
#pragma unroll
            for (int n = 0; n < 4; ++n) {
                short8 kf = *reinterpret_cast<const short8*>(&Ks[((kk * 4 + n) * 64 + lane) * 8]);
                s4[n] = mfma16(qv[kk], kf, s4[n]);
            }
        }

        const bool diag = (kt == j);
        float pm[4] = {-1e30f, -1e30f, -1e30f, -1e30f};
#pragma unroll
        for (int n = 0; n < 4; ++n) {
#pragma unroll
            for (int jj = 0; jj < 4; ++jj) {
                float v = s4[n][jj] * 0.0625f;  // 1/sqrt(256)
                if (diag) {
                    int rl = w * 16 + hi * 4 + jj, cl = n * 16 + lo;
                    if (cl > rl) v = -1e30f;    // causal mask
                }
                s4[n][jj] = v;
                pm[jj] = fmaxf(pm[jj], v);
            }
        }
#pragma unroll
        for (int off = 1; off < 16; off <<= 1)
#pragma unroll
            for (int jj = 0; jj < 4; ++jj)
                pm[jj] = fmaxf(pm[jj], __shfl_xor(pm[jj], off));

        float sc[4], lsum[4];
#pragma unroll
        for (int jj = 0; jj < 4; ++jj) {
            float mn = fmaxf(mrow[jj], pm[jj]);
            sc[jj] = __expf(mrow[jj] - mn);
            mrow[jj] = mn;
            lsum[jj] = 0.f;
        }
#pragma unroll
        for (int n = 0; n < 4; ++n)
#pragma unroll
            for (int jj = 0; jj < 4; ++jj) {
                float pv = __expf(s4[n][jj] - mrow[jj]);
                s4[n][jj] = pv;
                lsum[jj] += pv;
            }
#pragma unroll
        for (int off = 1; off < 16; off <<= 1)
#pragma unroll
            for (int jj = 0; jj < 4; ++jj)
                lsum[jj] += __shfl_xor(lsum[jj], off);
#pragma unroll
        for (int jj = 0; jj < 4; ++jj)
            lrow[jj] = lrow[jj] * sc[jj] + lsum[jj];
#pragma unroll
        for (int nf = 0; nf < 16; ++nf)
#pragma unroll
            for (int jj = 0; jj < 4; ++jj)
                o[nf][jj] *= sc[jj];

        // P (fp32, C/D layout) -> LDS -> A-frag layout (bf16); per-wave private
#pragma unroll
        for (int n = 0; n < 4; ++n)
#pragma unroll
            for (int jj = 0; jj < 4; ++jj)
                P[w][(hi * 4 + jj) * 64 + n * 16 + lo] = f2bf(s4[n][jj]);

#pragma unroll
        for (int k2 = 0; k2 < 2; ++k2) {
            short8 pa = *reinterpret_cast<const short8*>(&P[w][lo * 64 + k2 * 32 + hi * 8]);
#pragma unroll
            for (int nf = 0; nf < 16; ++nf) {
                short8 vf = *reinterpret_cast<const short8*>(&Vs[((k2 * 16 + nf) * 64 + lane) * 8]);
                o[nf] = mfma16(pa, vf, o[nf]);
            }
        }
        __syncthreads();                        // all reads done before next staging
    }

    if constexpr (DIRECT) {
        short* Sb = Sc + (size_t)b * S_LEN * D_DIM;
#pragma unroll
        for (int nf = 0; nf < 16; ++nf)
#pragma unroll
            for (int jj = 0; jj < 4; ++jj) {
                size_t row = q0 + w * 16 + hi * 4 + jj;
                Sb[row * D_DIM + nf * 16 + lo] = f2bf(o[nf][jj] / lrow[jj]);
            }
    } else {
        size_t pb = (size_t)(b * 64 + j) * NSPLIT + p;
        float* POb = PO + pb * (64 * 256);
        float* PMLb = PML + pb * 128;
#pragma unroll
        for (int nf = 0; nf < 16; ++nf)
#pragma unroll
            for (int jj = 0; jj < 4; ++jj)
                POb[(w * 16 + hi * 4 + jj) * 256 + nf * 16 + lo] = o[nf][jj];
        if (lo == 0)
#pragma unroll
            for (int jj = 0; jj < 4; ++jj) {
                PMLb[w * 16 + hi * 4 + jj] = mrow[jj];
                PMLb[64 + w * 16 + hi * 4 + jj] = lrow[jj];
            }
    }
}

// ---- merge NSPLIT partials -> S (bf16). Block = (b, j); thread owns 64 cols of a row ----
template <int NSPLIT>
__global__ __launch_bounds__(256) void attn_merge(
    const float* __restrict__ PO, const float* __restrict__ PML,
    short* __restrict__ Sc)
{
    const int bid = (int)blockIdx.x;        // b*64 + j
    const int b = bid >> 6, j = bid & 63;
    const int t = threadIdx.x;
    const int lr = t >> 2;                  // local row 0..63
    const int c0 = (t & 3) << 6;            // col base 0/64/128/192
    const size_t base = (size_t)bid * NSPLIT;

    float m[NSPLIT], l[NSPLIT], e[NSPLIT];
    float M = -1e30f;
#pragma unroll
    for (int p = 0; p < NSPLIT; ++p) {
        m[p] = PML[(base + p) * 128 + lr];
        l[p] = PML[(base + p) * 128 + 64 + lr];
        M = fmaxf(M, m[p]);
    }
    float L = 0.f;
#pragma unroll
    for (int p = 0; p < NSPLIT; ++p) { e[p] = __expf(m[p] - M); L += l[p] * e[p]; }
    const float inv = 1.0f / L;

    short* Sb = Sc + (size_t)b * S_LEN * D_DIM + (size_t)(j * 64 + lr) * D_DIM;
#pragma unroll
    for (int k = 0; k < 16; ++k) {
        f32x4 acc = {};
#pragma unroll
        for (int p = 0; p < NSPLIT; ++p) {
            f32x4 v = *reinterpret_cast<const f32x4*>(
                &PO[(base + p) * 16384 + (size_t)lr * 256 + c0 + k * 4]);
            acc += v * e[p];
        }
        s16x4 sv;
#pragma unroll
        for (int ii = 0; ii < 4; ++ii) sv[ii] = f2bf(acc[ii] * inv);
        *reinterpret_cast<s16x4*>(&Sb[c0 + k * 4]) = sv;
    }
}

extern "C" void kernel_launch(void* const* d_in, const int* in_sizes, int n_in,
                              void* d_out, int out_size, void* d_ws, size_t ws_size,
                              hipStream_t stream)
{
    const float* x  = (const float*)d_in[0];
    // d_in[1] = mask (int32 tril) — causality applied analytically, not read
    const float* wq = (const float*)d_in[2];
    const float* bq = (const float*)d_in[3];
    const float* wk = (const float*)d_in[4];
    const float* bk = (const float*)d_in[5];
    const float* wv = (const float*)d_in[6];
    const float* bv = (const float*)d_in[7];
    const float* wo = (const float*)d_in[8];
    const float* bo = (const float*)d_in[9];
    float* out = (float*)d_out;

    const size_t NTOK = (size_t)BATCH * S_LEN;          // 16384
    const size_t TD = NTOK * D_DIM;                     // 4,194,304
    short* WT = (short*)d_ws;                           // 4*65536 bf16
    short* xb = WT + 4 * 65536;
    short* QF = xb + TD;
    short* KF = QF + TD;
    short* VF = KF + TD;
    short* Sw = QF;    // alias: wave reads its own Q-frags before writing same S rows
    float* PO  = (float*)(VF + TD);
    const size_t fixed_b = (size_t)(4 * 65536 + 4 * TD) * 2;   // 34,078,720 B
    const size_t part_b  = (size_t)256 * (65536 + 512);        // per split: 16.9 MB

    const int M = (int)NTOK;

    xbf_conv<<<dim3(2048), 256, 0, stream>>>(x, xb);
    transpose_w<<<dim3(16, 16, 4), dim3(16, 16), 0, stream>>>(wq, wk, wv, wo, WT);
    gemm_bt<short, 1><<<dim3(2, M / 128), 256, 0, stream>>>(xb, WT,         bq, QF, M, 256, 256, 1);
    gemm_bt<short, 2><<<dim3(2, M / 128), 256, 0, stream>>>(xb, WT + 65536, bk, KF, M, 256, 256, 1);
    gemm_bt<short, 3><<<dim3(M / 128, 2), 256, 0, stream>>>(WT + 2 * 65536, xb, bv, VF, 256, M, M, 2);

    if (ws_size >= fixed_b + 2 * part_b) {
        float* PML = PO + (size_t)512 * 16384;
        attn_fwd<2, false><<<dim3(512), 256, 0, stream>>>(QF, KF, VF, PO, PML, Sw);
        attn_merge<2><<<dim3(256), 256, 0, stream>>>(PO, PML, Sw);
    } else if (ws_size >= fixed_b + part_b) {
        float* PML = PO + (size_t)256 * 16384;
        attn_fwd<1, false><<<dim3(256), 256, 0, stream>>>(QF, KF, VF, PO, PML, Sw);
        attn_merge<1><<<dim3(256), 256, 0, stream>>>(PO, PML, Sw);
    } else {
        attn_fwd<1, true><<<dim3(256), 256, 0, stream>>>(QF, KF, VF, nullptr, nullptr, Sw);
    }

    gemm_bt<float, 0><<<dim3(2, M / 128), 256, 0, stream>>>(Sw, WT + 3 * 65536, bo, out, M, 256, 256, 1);
}

// Round 9
// 162.896 us; speedup vs baseline: 3.9342x; 1.4056x over previous
//
#include <hip/hip_runtime.h>
#include <stdint.h>
#include <type_traits>

typedef __attribute__((ext_vector_type(8))) short short8;
typedef __attribute__((ext_vector_type(4))) short s16x4;
typedef __attribute__((ext_vector_type(4))) float f32x4;

#define S_LEN 4096
#define D_DIM 256
#define BATCH 4

__device__ __forceinline__ f32x4 mfma16(short8 a, short8 b, f32x4 c) {
    return __builtin_amdgcn_mfma_f32_16x16x32_bf16(a, b, c, 0, 0, 0);
}

// fp32 -> bf16 bits, round-to-nearest-even (matches numpy/ml_dtypes)
__device__ __forceinline__ short f2bf(float x) {
    uint32_t u = __float_as_uint(x);
    uint32_t r = (u + 0x7FFFu + ((u >> 16) & 1u)) >> 16;
    return (short)r;
}

// async global->LDS, 16B per lane. LDS dest wave-uniform base; HW adds lane*16.
__device__ __forceinline__ void gload16(const short* g, short* l) {
    __builtin_amdgcn_global_load_lds(
        (const __attribute__((address_space(1))) void*)g,
        (__attribute__((address_space(3))) void*)l, 16, 0, 0);
}

// ---- x fp32 -> bf16 ----
__global__ __launch_bounds__(256) void xbf_conv(
    const float* __restrict__ x, short* __restrict__ xb)
{
    int i = blockIdx.x * 256 + threadIdx.x;   // 8 elems per thread
    f32x4 a = *reinterpret_cast<const f32x4*>(x + (size_t)i * 8);
    f32x4 b = *reinterpret_cast<const f32x4*>(x + (size_t)i * 8 + 4);
    short8 r;
#pragma unroll
    for (int k = 0; k < 4; ++k) r[k] = f2bf(a[k]);
#pragma unroll
    for (int k = 0; k < 4; ++k) r[k + 4] = f2bf(b[k]);
    *reinterpret_cast<short8*>(xb + (size_t)i * 8) = r;
}

// ---- transpose four 256x256 fp32 weights into bf16 ws (WT[z][f][d] = W[z][d][f]) ----
__global__ __launch_bounds__(256) void transpose_w(
    const float* __restrict__ wq, const float* __restrict__ wk,
    const float* __restrict__ wv, const float* __restrict__ wo,
    short* __restrict__ out)
{
    __shared__ float t[16][17];
    const float* in = blockIdx.z == 0 ? wq : blockIdx.z == 1 ? wk
                    : blockIdx.z == 2 ? wv : wo;
    short* o = out + (size_t)blockIdx.z * 65536;
    const int x0 = blockIdx.x * 16, y0 = blockIdx.y * 16;
    const int tx = threadIdx.x, ty = threadIdx.y;
    t[ty][tx] = in[(y0 + ty) * 256 + x0 + tx];
    __syncthreads();
    o[(size_t)(x0 + ty) * 256 + y0 + tx] = f2bf(t[tx][ty]);
}

// ---- fused QKV GEMM: [16384 x 768] = xb[16384x256] * WT[768x256]^T + bias ----
// Output routed per 256-col region: Q-frag / K-frag / V-frag layouts (attn order).
__global__ __launch_bounds__(256) void gemm_qkv(
    const short* __restrict__ A, const short* __restrict__ Bt,
    const float* __restrict__ bq, const float* __restrict__ bk,
    const float* __restrict__ bv,
    short* __restrict__ QF, short* __restrict__ KF, short* __restrict__ VF)
{
    __shared__ short As[128 * 64];
    __shared__ short Bs[128 * 64];
    const int tid = threadIdx.x;
    const int lane = tid & 63;
    const int w = tid >> 6;
    const int wr = w >> 1, wc = w & 1;
    const int lo = lane & 15, hi = lane >> 4;
    const size_t m0 = (size_t)blockIdx.y * 128, n0 = (size_t)blockIdx.x * 128;
    const int reg = (int)(n0 >> 8);                  // 0=Q 1=K 2=V (block-uniform)
    const float* bias = reg == 0 ? bq : (reg == 1 ? bk : bv);

    f32x4 acc[4][4] = {};

    for (int kt = 0; kt < 4; ++kt) {
#pragma unroll
        for (int i = 0; i < 4; ++i) {
            int c = i * 4 + w;                     // wave chunk 0..15
            int s = c * 64 + lane;                 // 16B slot 0..1023
            int row = s >> 3, ke = (s & 7) * 8;    // 8 slots per 64-elem row
            gload16(A  + (m0 + row) * 256 + kt * 64 + ke, As + c * 512);
            gload16(Bt + (n0 + row) * 256 + kt * 64 + ke, Bs + c * 512);
        }
        __syncthreads();
#pragma unroll
        for (int kk = 0; kk < 2; ++kk) {
            short8 af[4], bf[4];
#pragma unroll
            for (int m = 0; m < 4; ++m)
                af[m] = *reinterpret_cast<const short8*>(&As[(wr * 64 + m * 16 + lo) * 64 + kk * 32 + hi * 8]);
#pragma unroll
            for (int n = 0; n < 4; ++n)
                bf[n] = *reinterpret_cast<const short8*>(&Bs[(wc * 64 + n * 16 + lo) * 64 + kk * 32 + hi * 8]);
#pragma unroll
            for (int m = 0; m < 4; ++m)
#pragma unroll
                for (int n = 0; n < 4; ++n)
                    acc[m][n] = mfma16(af[m], bf[n], acc[m][n]);
        }
        __syncthreads();
    }

#pragma unroll
    for (int m = 0; m < 4; ++m) {
#pragma unroll
        for (int n = 0; n < 4; ++n) {
#pragma unroll
            for (int j = 0; j < 4; ++j) {
                size_t row = m0 + wr * 64 + m * 16 + hi * 4 + j;
                int f = (int)((n0 + wc * 64 + n * 16 + lo) & 255);
                float v = acc[m][n][j] + bias[f];
                int b = (int)(row >> 12), R = (int)(row & 4095);
                if (reg == 0) {
                    int jt = R >> 4, lk = R & 15;
                    int kk = f >> 5, q = f & 31, hk = q >> 3, e = q & 7;
                    QF[((((size_t)(b * 256 + jt) * 8 + kk) * 64) + hk * 16 + lk) * 8 + e] = f2bf(v);
                } else if (reg == 1) {
                    int ktile = R >> 6, nn = (R >> 4) & 3, lk = R & 15;
                    int kk = f >> 5, q = f & 31, hk = q >> 3, e = q & 7;
                    KF[(((((size_t)(b * 64 + ktile) * 8 + kk) * 4 + nn) * 64) + hk * 16 + lk) * 8 + e] = f2bf(v);
                } else {  // V: row=token, col=feat -> VF[b][kt][k2][nf][lane][e]
                    int ktile = R >> 6, t6 = R & 63, k2 = t6 >> 5, r5 = t6 & 31;
                    int hk = r5 >> 3, e = r5 & 7;
                    int nf = f >> 4, lk = f & 15;
                    VF[(((((size_t)(b * 64 + ktile) * 2 + k2) * 16 + nf) * 64) + hk * 16 + lk) * 8 + e] = f2bf(v);
                }
            }
        }
    }
}

// ---- out-proj GEMM: C[M][N] = A[M][256]*Bt[N][256]^T + bias[col], fp32 out ----
__global__ __launch_bounds__(256) void gemm_out(
    const short* __restrict__ A, const short* __restrict__ Bt,
    const float* __restrict__ bias, float* __restrict__ C, int ldc)
{
    __shared__ short As[128 * 64];
    __shared__ short Bs[128 * 64];
    const int tid = threadIdx.x;
    const int lane = tid & 63;
    const int w = tid >> 6;
    const int wr = w >> 1, wc = w & 1;
    const int lo = lane & 15, hi = lane >> 4;
    const size_t m0 = (size_t)blockIdx.y * 128, n0 = (size_t)blockIdx.x * 128;

    f32x4 acc[4][4] = {};

    for (int kt = 0; kt < 4; ++kt) {
#pragma unroll
        for (int i = 0; i < 4; ++i) {
            int c = i * 4 + w;
            int s = c * 64 + lane;
            int row = s >> 3, ke = (s & 7) * 8;
            gload16(A  + (m0 + row) * 256 + kt * 64 + ke, As + c * 512);
            gload16(Bt + (n0 + row) * 256 + kt * 64 + ke, Bs + c * 512);
        }
        __syncthreads();
#pragma unroll
        for (int kk = 0; kk < 2; ++kk) {
            short8 af[4], bf[4];
#pragma unroll
            for (int m = 0; m < 4; ++m)
                af[m] = *reinterpret_cast<const short8*>(&As[(wr * 64 + m * 16 + lo) * 64 + kk * 32 + hi * 8]);
#pragma unroll
            for (int n = 0; n < 4; ++n)
                bf[n] = *reinterpret_cast<const short8*>(&Bs[(wc * 64 + n * 16 + lo) * 64 + kk * 32 + hi * 8]);
#pragma unroll
            for (int m = 0; m < 4; ++m)
#pragma unroll
                for (int n = 0; n < 4; ++n)
                    acc[m][n] = mfma16(af[m], bf[n], acc[m][n]);
        }
        __syncthreads();
    }

#pragma unroll
    for (int m = 0; m < 4; ++m)
#pragma unroll
        for (int n = 0; n < 4; ++n)
#pragma unroll
            for (int j = 0; j < 4; ++j) {
                size_t row = m0 + wr * 64 + m * 16 + hi * 4 + j;
                size_t col = n0 + wc * 64 + n * 16 + lo;
                C[row * (size_t)ldc + col] = acc[m][n][j] + bias[col];
            }
}

// ---- causal flash attention, double-buffered LDS K/V pipeline ----
// Block (j, b, p): 64-row q-block, wave w owns rows w*16..; k-tiles kt=p,p+NSPLIT,..<=j.
// 2-phase pipeline: STAGE(buf^1, t+1) issued BEFORE compute(buf); one barrier/tile
// (its vmcnt(0) drain doubles as the wait for t+1's staging).
template <int NSPLIT, bool DIRECT>
__global__ __launch_bounds__(256) void attn_fwd(
    const short* __restrict__ Qf, const short* __restrict__ Kf,
    const short* __restrict__ Vf, float* __restrict__ PO,
    float* __restrict__ PML, short* __restrict__ Sc)
{
    __shared__ short Ks[2][64 * 256];   // 2 x 32 KB
    __shared__ short Vs[2][64 * 256];   // 2 x 32 KB
    __shared__ short P[4][16 * 64];     // 8 KB

    const int tid = threadIdx.x;
    const int lane = tid & 63;
    const int w = tid >> 6;
    const int lo = lane & 15, hi = lane >> 4;
    const int bx = (int)blockIdx.x;
    const int j = 63 - bx / (BATCH * NSPLIT);   // LPT: longest q-blocks first
    const int r = bx % (BATCH * NSPLIT);
    const int b = r / NSPLIT;                   // batch pinned to 2 XCDs (NSPLIT=2)
    const int p = r % NSPLIT;
    const int q0 = j * 64;

    short8 qv[8];
#pragma unroll
    for (int kk = 0; kk < 8; ++kk)
        qv[kk] = *reinterpret_cast<const short8*>(
            Qf + (((size_t)(b * 256 + j * 4 + w) * 8 + kk) * 64 + lane) * 8);

    f32x4 o[16] = {};
    float mrow[4] = {-1e30f, -1e30f, -1e30f, -1e30f};
    float lrow[4] = {0.f, 0.f, 0.f, 0.f};

    auto stage = [&](int buf, int kt) {
        const short* Kt = Kf + (size_t)(b * 64 + kt) * 16384;
        const short* Vt = Vf + (size_t)(b * 64 + kt) * 16384;
#pragma unroll
        for (int c4 = 0; c4 < 8; ++c4) {
            int c = c4 * 4 + w;                 // 1KB chunk per call
            gload16(Kt + c * 512 + lane * 8, &Ks[buf][c * 512]);
            gload16(Vt + c * 512 + lane * 8, &Vs[buf][c * 512]);
        }
    };

    int cur = 0;
    if (p <= j) stage(0, p);
    __syncthreads();                            // staging of first tile complete

    for (int kt = p; kt <= j; kt += NSPLIT) {
        if (kt + NSPLIT <= j) stage(cur ^ 1, kt + NSPLIT);   // prefetch next tile

        f32x4 s4[4] = {};
#pragma unroll
        for (int kk = 0; kk < 8; ++kk) {
#pragma unroll
            for (int n = 0; n < 4; ++n) {
                short8 kf = *reinterpret_cast<const short8*>(&Ks[cur][((kk * 4 + n) * 64 + lane) * 8]);
                s4[n] = mfma16(qv[kk], kf, s4[n]);
            }
        }

        const bool diag = (kt == j);
        float pm[4] = {-1e30f, -1e30f, -1e30f, -1e30f};
#pragma unroll
        for (int n = 0; n < 4; ++n) {
#pragma unroll
            for (int jj = 0; jj < 4; ++jj) {
                float v = s4[n][jj] * 0.0625f;  // 1/sqrt(256)
                if (diag) {
                    int rl = w * 16 + hi * 4 + jj, cl = n * 16 + lo;
                    if (cl > rl) v = -1e30f;    // causal mask
                }
                s4[n][jj] = v;
                pm[jj] = fmaxf(pm[jj], v);
            }
        }
#pragma unroll
        for (int off = 1; off < 16; off <<= 1)
#pragma unroll
            for (int jj = 0; jj < 4; ++jj)
                pm[jj] = fmaxf(pm[jj], __shfl_xor(pm[jj], off));

        float sc[4], lsum[4];
#pragma unroll
        for (int jj = 0; jj < 4; ++jj) {
            float mn = fmaxf(mrow[jj], pm[jj]);
            sc[jj] = __expf(mrow[jj] - mn);
            mrow[jj] = mn;
            lsum[jj] = 0.f;
        }
#pragma unroll
        for (int n = 0; n < 4; ++n)
#pragma unroll
            for (int jj = 0; jj < 4; ++jj) {
                float pv = __expf(s4[n][jj] - mrow[jj]);
                s4[n][jj] = pv;
                lsum[jj] += pv;
            }
#pragma unroll
        for (int off = 1; off < 16; off <<= 1)
#pragma unroll
            for (int jj = 0; jj < 4; ++jj)
                lsum[jj] += __shfl_xor(lsum[jj], off);
#pragma unroll
        for (int jj = 0; jj < 4; ++jj)
            lrow[jj] = lrow[jj] * sc[jj] + lsum[jj];
#pragma unroll
        for (int nf = 0; nf < 16; ++nf)
#pragma unroll
            for (int jj = 0; jj < 4; ++jj)
                o[nf][jj] *= sc[jj];

        // P (fp32, C/D layout) -> LDS -> A-frag layout (bf16); per-wave private
#pragma unroll
        for (int n = 0; n < 4; ++n)
#pragma unroll
            for (int jj = 0; jj < 4; ++jj)
                P[w][(hi * 4 + jj) * 64 + n * 16 + lo] = f2bf(s4[n][jj]);

#pragma unroll
        for (int k2 = 0; k2 < 2; ++k2) {
            short8 pa = *reinterpret_cast<const short8*>(&P[w][lo * 64 + k2 * 32 + hi * 8]);
#pragma unroll
            for (int nf = 0; nf < 16; ++nf) {
                short8 vf = *reinterpret_cast<const short8*>(&Vs[cur][((k2 * 16 + nf) * 64 + lane) * 8]);
                o[nf] = mfma16(pa, vf, o[nf]);
            }
        }
        __syncthreads();   // drains prefetch (vmcnt0) + protects P/buffers
        cur ^= 1;
    }

    if constexpr (DIRECT) {
        short* Sb = Sc + (size_t)b * S_LEN * D_DIM;
#pragma unroll
        for (int nf = 0; nf < 16; ++nf)
#pragma unroll
            for (int jj = 0; jj < 4; ++jj) {
                size_t row = q0 + w * 16 + hi * 4 + jj;
                Sb[row * D_DIM + nf * 16 + lo] = f2bf(o[nf][jj] / lrow[jj]);
            }
    } else {
        size_t pb = (size_t)(b * 64 + j) * NSPLIT + p;
        float* POb = PO + pb * (64 * 256);
        float* PMLb = PML + pb * 128;
#pragma unroll
        for (int nf = 0; nf < 16; ++nf)
#pragma unroll
            for (int jj = 0; jj < 4; ++jj)
                POb[(w * 16 + hi * 4 + jj) * 256 + nf * 16 + lo] = o[nf][jj];
        if (lo == 0)
#pragma unroll
            for (int jj = 0; jj < 4; ++jj) {
                PMLb[w * 16 + hi * 4 + jj] = mrow[jj];
                PMLb[64 + w * 16 + hi * 4 + jj] = lrow[jj];
            }
    }
}

// ---- merge NSPLIT partials -> S (bf16). Block = (b, j); thread owns 64 cols of a row ----
template <int NSPLIT>
__global__ __launch_bounds__(256) void attn_merge(
    const float* __restrict__ PO, const float* __restrict__ PML,
    short* __restrict__ Sc)
{
    const int bid = (int)blockIdx.x;        // b*64 + j
    const int b = bid >> 6, j = bid & 63;
    const int t = threadIdx.x;
    const int lr = t >> 2;                  // local row 0..63
    const int c0 = (t & 3) << 6;            // col base 0/64/128/192
    const size_t base = (size_t)bid * NSPLIT;

    float m[NSPLIT], l[NSPLIT], e[NSPLIT];
    float M = -1e30f;
#pragma unroll
    for (int p = 0; p < NSPLIT; ++p) {
        m[p] = PML[(base + p) * 128 + lr];
        l[p] = PML[(base + p) * 128 + 64 + lr];
        M = fmaxf(M, m[p]);
    }
    float L = 0.f;
#pragma unroll
    for (int p = 0; p < NSPLIT; ++p) { e[p] = __expf(m[p] - M); L += l[p] * e[p]; }
    const float inv = 1.0f / L;

    short* Sb = Sc + (size_t)b * S_LEN * D_DIM + (size_t)(j * 64 + lr) * D_DIM;
#pragma unroll
    for (int k = 0; k < 16; ++k) {
        f32x4 acc = {};
#pragma unroll
        for (int p = 0; p < NSPLIT; ++p) {
            f32x4 v = *reinterpret_cast<const f32x4*>(
                &PO[(base + p) * 16384 + (size_t)lr * 256 + c0 + k * 4]);
            acc += v * e[p];
        }
        s16x4 sv;
#pragma unroll
        for (int ii = 0; ii < 4; ++ii) sv[ii] = f2bf(acc[ii] * inv);
        *reinterpret_cast<s16x4*>(&Sb[c0 + k * 4]) = sv;
    }
}

extern "C" void kernel_launch(void* const* d_in, const int* in_sizes, int n_in,
                              void* d_out, int out_size, void* d_ws, size_t ws_size,
                              hipStream_t stream)
{
    const float* x  = (const float*)d_in[0];
    // d_in[1] = mask (int32 tril) — causality applied analytically, not read
    const float* wq = (const float*)d_in[2];
    const float* bq = (const float*)d_in[3];
    const float* wk = (const float*)d_in[4];
    const float* bk = (const float*)d_in[5];
    const float* wv = (const float*)d_in[6];
    const float* bv = (const float*)d_in[7];
    const float* wo = (const float*)d_in[8];
    const float* bo = (const float*)d_in[9];
    float* out = (float*)d_out;

    const size_t NTOK = (size_t)BATCH * S_LEN;          // 16384
    const size_t TD = NTOK * D_DIM;                     // 4,194,304
    short* WT = (short*)d_ws;                           // 4*65536 bf16 [Wq;Wk;Wv;Wo] transposed
    short* xb = WT + 4 * 65536;
    short* QF = xb + TD;
    short* KF = QF + TD;
    short* VF = KF + TD;
    short* Sw = QF;    // alias: attn reads its own Q-frags, then only merge writes S
    float* PO  = (float*)(VF + TD);
    const size_t fixed_b = (size_t)(4 * 65536 + 4 * TD) * 2;   // 34,078,720 B
    const size_t part_b  = (size_t)256 * (65536 + 512);        // per split: 16.9 MB

    const int M = (int)NTOK;

    xbf_conv<<<dim3(2048), 256, 0, stream>>>(x, xb);
    transpose_w<<<dim3(16, 16, 4), dim3(16, 16), 0, stream>>>(wq, wk, wv, wo, WT);
    gemm_qkv<<<dim3(6, M / 128), 256, 0, stream>>>(xb, WT, bq, bk, bv, QF, KF, VF);

    if (ws_size >= fixed_b + 2 * part_b) {
        float* PML = PO + (size_t)512 * 16384;
        attn_fwd<2, false><<<dim3(512), 256, 0, stream>>>(QF, KF, VF, PO, PML, Sw);
        attn_merge<2><<<dim3(256), 256, 0, stream>>>(PO, PML, Sw);
    } else if (ws_size >= fixed_b + part_b) {
        float* PML = PO + (size_t)256 * 16384;
        attn_fwd<1, false><<<dim3(256), 256, 0, stream>>>(QF, KF, VF, PO, PML, Sw);
        attn_merge<1><<<dim3(256), 256, 0, stream>>>(PO, PML, Sw);
    } else {
        attn_fwd<1, true><<<dim3(256), 256, 0, stream>>>(QF, KF, VF, nullptr, nullptr, Sw);
    }

    gemm_out<<<dim3(2, M / 128), 256, 0, stream>>>(Sw, WT + 3 * 65536, bo, out, 256);
}

// Round 10
// 157.771 us; speedup vs baseline: 4.0619x; 1.0325x over previous
//
#include <hip/hip_runtime.h>
#include <stdint.h>
#include <type_traits>

typedef __attribute__((ext_vector_type(8))) short short8;
typedef __attribute__((ext_vector_type(4))) short s16x4;
typedef __attribute__((ext_vector_type(4))) float f32x4;

#define S_LEN 4096
#define D_DIM 256
#define BATCH 4

__device__ __forceinline__ f32x4 mfma16(short8 a, short8 b, f32x4 c) {
    return __builtin_amdgcn_mfma_f32_16x16x32_bf16(a, b, c, 0, 0, 0);
}

// fp32 -> bf16 bits, round-to-nearest-even (matches numpy/ml_dtypes)
__device__ __forceinline__ short f2bf(float x) {
    uint32_t u = __float_as_uint(x);
    uint32_t r = (u + 0x7FFFu + ((u >> 16) & 1u)) >> 16;
    return (short)r;
}

// async global->LDS, 16B per lane. LDS dest wave-uniform base; HW adds lane*16.
__device__ __forceinline__ void gload16(const short* g, short* l) {
    __builtin_amdgcn_global_load_lds(
        (const __attribute__((address_space(1))) void*)g,
        (__attribute__((address_space(3))) void*)l, 16, 0, 0);
}

// ---- x fp32 -> bf16 ----
__global__ __launch_bounds__(256) void xbf_conv(
    const float* __restrict__ x, short* __restrict__ xb)
{
    int i = blockIdx.x * 256 + threadIdx.x;   // 8 elems per thread
    f32x4 a = *reinterpret_cast<const f32x4*>(x + (size_t)i * 8);
    f32x4 b = *reinterpret_cast<const f32x4*>(x + (size_t)i * 8 + 4);
    short8 r;
#pragma unroll
    for (int k = 0; k < 4; ++k) r[k] = f2bf(a[k]);
#pragma unroll
    for (int k = 0; k < 4; ++k) r[k + 4] = f2bf(b[k]);
    *reinterpret_cast<short8*>(xb + (size_t)i * 8) = r;
}

// ---- transpose four 256x256 fp32 weights into bf16 ws (WT[z][f][d] = W[z][d][f]) ----
__global__ __launch_bounds__(256) void transpose_w(
    const float* __restrict__ wq, const float* __restrict__ wk,
    const float* __restrict__ wv, const float* __restrict__ wo,
    short* __restrict__ out)
{
    __shared__ float t[16][17];
    const float* in = blockIdx.z == 0 ? wq : blockIdx.z == 1 ? wk
                    : blockIdx.z == 2 ? wv : wo;
    short* o = out + (size_t)blockIdx.z * 65536;
    const int x0 = blockIdx.x * 16, y0 = blockIdx.y * 16;
    const int tx = threadIdx.x, ty = threadIdx.y;
    t[ty][tx] = in[(y0 + ty) * 256 + x0 + tx];
    __syncthreads();
    o[(size_t)(x0 + ty) * 256 + y0 + tx] = f2bf(t[tx][ty]);
}

// ---- fused QKV GEMM: [16384 x 768] = xb[16384x256] * WT[768x256]^T + bias ----
// Output routed per 256-col region: Q-frag / K-frag / V-frag layouts (attn order).
__global__ __launch_bounds__(256) void gemm_qkv(
    const short* __restrict__ A, const short* __restrict__ Bt,
    const float* __restrict__ bq, const float* __restrict__ bk,
    const float* __restrict__ bv,
    short* __restrict__ QF, short* __restrict__ KF, short* __restrict__ VF)
{
    __shared__ short As[128 * 64];
    __shared__ short Bs[128 * 64];
    const int tid = threadIdx.x;
    const int lane = tid & 63;
    const int w = tid >> 6;
    const int wr = w >> 1, wc = w & 1;
    const int lo = lane & 15, hi = lane >> 4;
    const size_t m0 = (size_t)blockIdx.y * 128, n0 = (size_t)blockIdx.x * 128;
    const int reg = (int)(n0 >> 8);                  // 0=Q 1=K 2=V (block-uniform)
    const float* bias = reg == 0 ? bq : (reg == 1 ? bk : bv);

    f32x4 acc[4][4] = {};

    for (int kt = 0; kt < 4; ++kt) {
#pragma unroll
        for (int i = 0; i < 4; ++i) {
            int c = i * 4 + w;                     // wave chunk 0..15
            int s = c * 64 + lane;                 // 16B slot 0..1023
            int row = s >> 3, ke = (s & 7) * 8;    // 8 slots per 64-elem row
            gload16(A  + (m0 + row) * 256 + kt * 64 + ke, As + c * 512);
            gload16(Bt + (n0 + row) * 256 + kt * 64 + ke, Bs + c * 512);
        }
        __syncthreads();
#pragma unroll
        for (int kk = 0; kk < 2; ++kk) {
            short8 af[4], bf[4];
#pragma unroll
            for (int m = 0; m < 4; ++m)
                af[m] = *reinterpret_cast<const short8*>(&As[(wr * 64 + m * 16 + lo) * 64 + kk * 32 + hi * 8]);
#pragma unroll
            for (int n = 0; n < 4; ++n)
                bf[n] = *reinterpret_cast<const short8*>(&Bs[(wc * 64 + n * 16 + lo) * 64 + kk * 32 + hi * 8]);
#pragma unroll
            for (int m = 0; m < 4; ++m)
#pragma unroll
                for (int n = 0; n < 4; ++n)
                    acc[m][n] = mfma16(af[m], bf[n], acc[m][n]);
        }
        __syncthreads();
    }

#pragma unroll
    for (int m = 0; m < 4; ++m) {
#pragma unroll
        for (int n = 0; n < 4; ++n) {
#pragma unroll
            for (int j = 0; j < 4; ++j) {
                size_t row = m0 + wr * 64 + m * 16 + hi * 4 + j;
                int f = (int)((n0 + wc * 64 + n * 16 + lo) & 255);
                float v = acc[m][n][j] + bias[f];
                int b = (int)(row >> 12), R = (int)(row & 4095);
                if (reg == 0) {
                    int jt = R >> 4, lk = R & 15;
                    int kk = f >> 5, q = f & 31, hk = q >> 3, e = q & 7;
                    QF[((((size_t)(b * 256 + jt) * 8 + kk) * 64) + hk * 16 + lk) * 8 + e] = f2bf(v);
                } else if (reg == 1) {
                    int ktile = R >> 6, nn = (R >> 4) & 3, lk = R & 15;
                    int kk = f >> 5, q = f & 31, hk = q >> 3, e = q & 7;
                    KF[(((((size_t)(b * 64 + ktile) * 8 + kk) * 4 + nn) * 64) + hk * 16 + lk) * 8 + e] = f2bf(v);
                } else {  // V: row=token, col=feat -> VF[b][kt][k2][nf][lane][e]
                    int ktile = R >> 6, t6 = R & 63, k2 = t6 >> 5, r5 = t6 & 31;
                    int hk = r5 >> 3, e = r5 & 7;
                    int nf = f >> 4, lk = f & 15;
                    VF[(((((size_t)(b * 64 + ktile) * 2 + k2) * 16 + nf) * 64) + hk * 16 + lk) * 8 + e] = f2bf(v);
                }
            }
        }
    }
}

// ---- out-proj GEMM: C[M][N] = A[M][256]*Bt[N][256]^T + bias[col], fp32 out ----
__global__ __launch_bounds__(256) void gemm_out(
    const short* __restrict__ A, const short* __restrict__ Bt,
    const float* __restrict__ bias, float* __restrict__ C, int ldc)
{
    __shared__ short As[128 * 64];
    __shared__ short Bs[128 * 64];
    const int tid = threadIdx.x;
    const int lane = tid & 63;
    const int w = tid >> 6;
    const int wr = w >> 1, wc = w & 1;
    const int lo = lane & 15, hi = lane >> 4;
    const size_t m0 = (size_t)blockIdx.y * 128, n0 = (size_t)blockIdx.x * 128;

    f32x4 acc[4][4] = {};

    for (int kt = 0; kt < 4; ++kt) {
#pragma unroll
        for (int i = 0; i < 4; ++i) {
            int c = i * 4 + w;
            int s = c * 64 + lane;
            int row = s >> 3, ke = (s & 7) * 8;
            gload16(A  + (m0 + row) * 256 + kt * 64 + ke, As + c * 512);
            gload16(Bt + (n0 + row) * 256 + kt * 64 + ke, Bs + c * 512);
        }
        __syncthreads();
#pragma unroll
        for (int kk = 0; kk < 2; ++kk) {
            short8 af[4], bf[4];
#pragma unroll
            for (int m = 0; m < 4; ++m)
                af[m] = *reinterpret_cast<const short8*>(&As[(wr * 64 + m * 16 + lo) * 64 + kk * 32 + hi * 8]);
#pragma unroll
            for (int n = 0; n < 4; ++n)
                bf[n] = *reinterpret_cast<const short8*>(&Bs[(wc * 64 + n * 16 + lo) * 64 + kk * 32 + hi * 8]);
#pragma unroll
            for (int m = 0; m < 4; ++m)
#pragma unroll
                for (int n = 0; n < 4; ++n)
                    acc[m][n] = mfma16(af[m], bf[n], acc[m][n]);
        }
        __syncthreads();
    }

#pragma unroll
    for (int m = 0; m < 4; ++m)
#pragma unroll
        for (int n = 0; n < 4; ++n)
#pragma unroll
            for (int j = 0; j < 4; ++j) {
                size_t row = m0 + wr * 64 + m * 16 + hi * 4 + j;
                size_t col = n0 + wc * 64 + n * 16 + lo;
                C[row * (size_t)ldc + col] = acc[m][n][j] + bias[col];
            }
}

// ---- causal flash attention: mirror-paired blocks + parity split-K ----
// Block bx -> (pair m, batch b, parity p). Processes q-block j = 63-m THEN j = m:
// work = (64-m)/NSPLIT + (m+1)/NSPLIT ~ constant -> perfect static balance.
// Single-buffered K/V (72KB LDS -> 2 blocks/CU = 2 waves/SIMD; cross-block overlap
// hides stage drain). k-tiles kt = p, p+NSPLIT, ..., <= j.
template <int NSPLIT, bool DIRECT>
__global__ __launch_bounds__(256) void attn_fwd(
    const short* __restrict__ Qf, const short* __restrict__ Kf,
    const short* __restrict__ Vf, float* __restrict__ PO,
    float* __restrict__ PML, short* __restrict__ Sc)
{
    __shared__ short Ks[64 * 256];   // 32 KB
    __shared__ short Vs[64 * 256];   // 32 KB
    __shared__ short P[4][16 * 64];  // 8 KB

    const int tid = threadIdx.x;
    const int lane = tid & 63;
    const int w = tid >> 6;
    const int lo = lane & 15, hi = lane >> 4;
    const int bx = (int)blockIdx.x;
    const int m = bx / (BATCH * NSPLIT);        // pair id 0..31
    const int r = bx % (BATCH * NSPLIT);
    const int b = r / NSPLIT;                   // bx%8 pins batch to 2 XCDs (NSPLIT=2)
    const int p = r % NSPLIT;

    for (int half = 0; half < 2; ++half) {
        const int j = half == 0 ? (63 - m) : m;   // long sub-block first
        const int q0 = j * 64;

        short8 qv[8];
#pragma unroll
        for (int kk = 0; kk < 8; ++kk)
            qv[kk] = *reinterpret_cast<const short8*>(
                Qf + (((size_t)(b * 256 + j * 4 + w) * 8 + kk) * 64 + lane) * 8);

        f32x4 o[16] = {};
        float mrow[4] = {-1e30f, -1e30f, -1e30f, -1e30f};
        float lrow[4] = {0.f, 0.f, 0.f, 0.f};

        for (int kt = p; kt <= j; kt += NSPLIT) {
            const short* Kt = Kf + (size_t)(b * 64 + kt) * 16384;
            const short* Vt = Vf + (size_t)(b * 64 + kt) * 16384;
#pragma unroll
            for (int c4 = 0; c4 < 8; ++c4) {
                int c = c4 * 4 + w;                 // 1KB chunk per call
                gload16(Kt + c * 512 + lane * 8, &Ks[c * 512]);
                gload16(Vt + c * 512 + lane * 8, &Vs[c * 512]);
            }
            __syncthreads();                        // drains vmcnt -> tile ready

            f32x4 s4[4] = {};
            __builtin_amdgcn_s_setprio(1);
#pragma unroll
            for (int kk = 0; kk < 8; ++kk) {
#pragma unroll
                for (int n = 0; n < 4; ++n) {
                    short8 kf = *reinterpret_cast<const short8*>(&Ks[((kk * 4 + n) * 64 + lane) * 8]);
                    s4[n] = mfma16(qv[kk], kf, s4[n]);
                }
            }
            __builtin_amdgcn_s_setprio(0);

            const bool diag = (kt == j);
            float pm[4] = {-1e30f, -1e30f, -1e30f, -1e30f};
#pragma unroll
            for (int n = 0; n < 4; ++n) {
#pragma unroll
                for (int jj = 0; jj < 4; ++jj) {
                    float v = s4[n][jj] * 0.0625f;  // 1/sqrt(256)
                    if (diag) {
                        int rl = w * 16 + hi * 4 + jj, cl = n * 16 + lo;
                        if (cl > rl) v = -1e30f;    // causal mask
                    }
                    s4[n][jj] = v;
                    pm[jj] = fmaxf(pm[jj], v);
                }
            }
#pragma unroll
            for (int off = 1; off < 16; off <<= 1)
#pragma unroll
                for (int jj = 0; jj < 4; ++jj)
                    pm[jj] = fmaxf(pm[jj], __shfl_xor(pm[jj], off));

            float sc[4], lsum[4];
#pragma unroll
            for (int jj = 0; jj < 4; ++jj) {
                float mn = fmaxf(mrow[jj], pm[jj]);
                sc[jj] = __expf(mrow[jj] - mn);
                mrow[jj] = mn;
                lsum[jj] = 0.f;
            }
#pragma unroll
            for (int n = 0; n < 4; ++n)
#pragma unroll
                for (int jj = 0; jj < 4; ++jj) {
                    float pv = __expf(s4[n][jj] - mrow[jj]);
                    s4[n][jj] = pv;
                    lsum[jj] += pv;
                }
#pragma unroll
            for (int off = 1; off < 16; off <<= 1)
#pragma unroll
                for (int jj = 0; jj < 4; ++jj)
                    lsum[jj] += __shfl_xor(lsum[jj], off);
#pragma unroll
            for (int jj = 0; jj < 4; ++jj)
                lrow[jj] = lrow[jj] * sc[jj] + lsum[jj];
#pragma unroll
            for (int nf = 0; nf < 16; ++nf)
#pragma unroll
                for (int jj = 0; jj < 4; ++jj)
                    o[nf][jj] *= sc[jj];

            // P (fp32, C/D layout) -> LDS -> A-frag layout (bf16); per-wave private
#pragma unroll
            for (int n = 0; n < 4; ++n)
#pragma unroll
                for (int jj = 0; jj < 4; ++jj)
                    P[w][(hi * 4 + jj) * 64 + n * 16 + lo] = f2bf(s4[n][jj]);

            __builtin_amdgcn_s_setprio(1);
#pragma unroll
            for (int k2 = 0; k2 < 2; ++k2) {
                short8 pa = *reinterpret_cast<const short8*>(&P[w][lo * 64 + k2 * 32 + hi * 8]);
#pragma unroll
                for (int nf = 0; nf < 16; ++nf) {
                    short8 vf = *reinterpret_cast<const short8*>(&Vs[((k2 * 16 + nf) * 64 + lane) * 8]);
                    o[nf] = mfma16(pa, vf, o[nf]);
                }
            }
            __builtin_amdgcn_s_setprio(0);
            __syncthreads();                        // all reads done before next stage
        }

        if constexpr (DIRECT) {
            short* Sb = Sc + (size_t)b * S_LEN * D_DIM;
#pragma unroll
            for (int nf = 0; nf < 16; ++nf)
#pragma unroll
                for (int jj = 0; jj < 4; ++jj) {
                    size_t row = q0 + w * 16 + hi * 4 + jj;
                    Sb[row * D_DIM + nf * 16 + lo] = f2bf(o[nf][jj] / lrow[jj]);
                }
        } else {
            size_t pb = (size_t)(b * 64 + j) * NSPLIT + p;
            float* POb = PO + pb * (64 * 256);
            float* PMLb = PML + pb * 128;
#pragma unroll
            for (int nf = 0; nf < 16; ++nf)
#pragma unroll
                for (int jj = 0; jj < 4; ++jj)
                    POb[(w * 16 + hi * 4 + jj) * 256 + nf * 16 + lo] = o[nf][jj];
            if (lo == 0)
#pragma unroll
                for (int jj = 0; jj < 4; ++jj) {
                    PMLb[w * 16 + hi * 4 + jj] = mrow[jj];
                    PMLb[64 + w * 16 + hi * 4 + jj] = lrow[jj];
                }
        }
    }
}

// ---- merge NSPLIT partials -> S (bf16). Block = (b, j); thread owns 64 cols of a row ----
template <int NSPLIT>
__global__ __launch_bounds__(256) void attn_merge(
    const float* __restrict__ PO, const float* __restrict__ PML,
    short* __restrict__ Sc)
{
    const int bid = (int)blockIdx.x;        // b*64 + j
    const int b = bid >> 6, j = bid & 63;
    const int t = threadIdx.x;
    const int lr = t >> 2;                  // local row 0..63
    const int c0 = (t & 3) << 6;            // col base 0/64/128/192
    const size_t base = (size_t)bid * NSPLIT;

    float m[NSPLIT], l[NSPLIT], e[NSPLIT];
    float M = -1e30f;
#pragma unroll
    for (int p = 0; p < NSPLIT; ++p) {
        m[p] = PML[(base + p) * 128 + lr];
        l[p] = PML[(base + p) * 128 + 64 + lr];
        M = fmaxf(M, m[p]);
    }
    float L = 0.f;
#pragma unroll
    for (int p = 0; p < NSPLIT; ++p) { e[p] = __expf(m[p] - M); L += l[p] * e[p]; }
    const float inv = 1.0f / L;

    short* Sb = Sc + (size_t)b * S_LEN * D_DIM + (size_t)(j * 64 + lr) * D_DIM;
#pragma unroll
    for (int k = 0; k < 16; ++k) {
        f32x4 acc = {};
#pragma unroll
        for (int p = 0; p < NSPLIT; ++p) {
            f32x4 v = *reinterpret_cast<const f32x4*>(
                &PO[(base + p) * 16384 + (size_t)lr * 256 + c0 + k * 4]);
            acc += v * e[p];
        }
        s16x4 sv;
#pragma unroll
        for (int ii = 0; ii < 4; ++ii) sv[ii] = f2bf(acc[ii] * inv);
        *reinterpret_cast<s16x4*>(&Sb[c0 + k * 4]) = sv;
    }
}

extern "C" void kernel_launch(void* const* d_in, const int* in_sizes, int n_in,
                              void* d_out, int out_size, void* d_ws, size_t ws_size,
                              hipStream_t stream)
{
    const float* x  = (const float*)d_in[0];
    // d_in[1] = mask (int32 tril) — causality applied analytically, not read
    const float* wq = (const float*)d_in[2];
    const float* bq = (const float*)d_in[3];
    const float* wk = (const float*)d_in[4];
    const float* bk = (const float*)d_in[5];
    const float* wv = (const float*)d_in[6];
    const float* bv = (const float*)d_in[7];
    const float* wo = (const float*)d_in[8];
    const float* bo = (const float*)d_in[9];
    float* out = (float*)d_out;

    const size_t NTOK = (size_t)BATCH * S_LEN;          // 16384
    const size_t TD = NTOK * D_DIM;                     // 4,194,304
    short* WT = (short*)d_ws;                           // 4*65536 bf16 [Wq;Wk;Wv;Wo] transposed
    short* xb = WT + 4 * 65536;
    short* QF = xb + TD;
    short* KF = QF + TD;
    short* VF = KF + TD;
    short* Sw = QF;    // alias: attn reads its own Q-frags; only merge writes S (after attn)
    float* PO  = (float*)(VF + TD);
    const size_t fixed_b = (size_t)(4 * 65536 + 4 * TD) * 2;   // 34,078,720 B
    const size_t part_b  = (size_t)256 * (65536 + 512);        // per split: 16.9 MB

    const int M = (int)NTOK;

    xbf_conv<<<dim3(2048), 256, 0, stream>>>(x, xb);
    transpose_w<<<dim3(16, 16, 4), dim3(16, 16), 0, stream>>>(wq, wk, wv, wo, WT);
    gemm_qkv<<<dim3(6, M / 128), 256, 0, stream>>>(xb, WT, bq, bk, bv, QF, KF, VF);

    if (ws_size >= fixed_b + 2 * part_b) {
        float* PML = PO + (size_t)512 * 16384;
        attn_fwd<2, false><<<dim3(32 * BATCH * 2), 256, 0, stream>>>(QF, KF, VF, PO, PML, Sw);
        attn_merge<2><<<dim3(256), 256, 0, stream>>>(PO, PML, Sw);
    } else if (ws_size >= fixed_b + part_b) {
        float* PML = PO + (size_t)256 * 16384;
        attn_fwd<1, false><<<dim3(32 * BATCH), 256, 0, stream>>>(QF, KF, VF, PO, PML, Sw);
        attn_merge<1><<<dim3(256), 256, 0, stream>>>(PO, PML, Sw);
    } else {
        attn_fwd<1, true><<<dim3(32 * BATCH), 256, 0, stream>>>(QF, KF, VF, nullptr, nullptr, Sw);
    }

    gemm_out<<<dim3(2, M / 128), 256, 0, stream>>>(Sw, WT + 3 * 65536, bo, out, 256);
}